// Round 12
// baseline (1374.800 us; speedup 1.0000x reference)
//
#include <hip/hip_runtime.h>
#include <math.h>

#define BATCH 1024
#define TSEQ  2048
#define DIN   5
#define H     64
#define BT    4      // elems per block; grid 256 = every CU
#define DEP   4      // ring depth (power of 2)
#define RSTR  80     // halves per elem per ring slot: 40 words = 8 mod 32 -> 2-way banks (free)
#define NOUT  128

typedef _Float16 f16x8 __attribute__((ext_vector_type(8)));
typedef float    f32x4 __attribute__((ext_vector_type(4)));

#if __has_builtin(__builtin_amdgcn_rcpf)
__device__ __forceinline__ float rcp_fast(float x) { return __builtin_amdgcn_rcpf(x); }
#else
__device__ __forceinline__ float rcp_fast(float x) { return 1.0f / x; }
#endif

#define LOG2E 1.44269504088896f

__device__ __forceinline__ float sigm2(float s) {   // s = log2e * p
    return rcp_fast(1.0f + __builtin_amdgcn_exp2f(-s));
}
__device__ __forceinline__ float tanh2(float s) {   // s = 2*log2e * p
    return fmaf(-2.0f, rcp_fast(__builtin_amdgcn_exp2f(s) + 1.0f), 1.0f);
}

__device__ __forceinline__ int imin(int a, int b) { return a < b ? a : b; }

// Poll 4 per-wave flags (broadcast LDS reads) until min >= tgt; acquire fence
// on success. Callers cache the return so satisfied checks cost zero LDS ops
// (visibility was established by the fence at the earlier successful poll).
__device__ __forceinline__ int wait_min_ge(const int* p, int tgt) {
    volatile const int* v = p;
    int m;
    do {
        int a = v[0], b = v[1], c = v[2], d = v[3];
        m = imin(imin(a, b), imin(c, d));
    } while (m < tgt);
    __threadfence_block();
    return m;
}

// r11's lean chains + flag-decoupled wave groups (no __syncthreads in loop).
// Waves 0-3 (lay-1): K=64 MFMA (x folded via register-precomputed dx) -> G1,
// publish h1(t) into ring1[t&3], bump own flag flg[ww] (plain ds_write).
// Waves 4-7 (lay-2): K=128 MFMA (h2-first order so its 2 MFMAs issue before
// the y1 flag check) -> G2, publish h2 into ring2, bump flg[4+ww].
// Groups are internally lockstep (the recurrence demands it) but drift up to
// DEP timesteps against each other -> lay-1 MFMA bursts overlap lay-2 trans.
__global__ __launch_bounds__(512)
void lstm_pipe(const float* __restrict__ x,
               const float* __restrict__ Wih0, const float* __restrict__ Whh0,
               const float* __restrict__ bih0, const float* __restrict__ bhh0,
               const float* __restrict__ Wih1, const float* __restrict__ Whh1,
               const float* __restrict__ bih1, const float* __restrict__ bhh1,
               const float* __restrict__ Wfc,  const float* __restrict__ bfc,
               float* __restrict__ out)
{
    __shared__ alignas(16) _Float16 ring1[DEP][BT * RSTR];  // 2.5 KB h1 ring
    __shared__ alignas(16) _Float16 ring2[DEP][BT * RSTR];  // 2.5 KB h2 ring
    __shared__ alignas(16) float    h2f[BT][H];             // 1 KB FC input
    __shared__ alignas(16) int      flg[8];                 // [0:4)=lay1, [4:8)=lay2

    const int tid  = threadIdx.x;
    const int w    = tid >> 6;         // 0..7
    const int lane = tid & 63;
    const int col  = lane & 15;        // n (h-unit offset); A-row m
    const int q    = lane >> 4;        // quad -> G elem; k-slice
    const int ww   = w & 3;            // h-unit tile
    const int lay  = w >> 2;           // 0 = layer-1 group, 1 = layer-2 group
    const int hu   = 16 * ww + col;
    const int b0   = blockIdx.x * BT;

    for (int j = tid; j < DEP * BT * RSTR; j += 512) {
        ((_Float16*)ring1)[j] = (_Float16)0.0f;
        ((_Float16*)ring2)[j] = (_Float16)0.0f;
    }
    if (tid < 8) flg[tid] = 0;

    const float sgl[4] = {LOG2E, LOG2E, 2.0f * LOG2E, LOG2E};  // i,f,g,o

    // ---- B-fragments for THIS wave's layer (registers, pre-scaled) ----
    // B[k=q*8+j][n=col]; n-tile g = gate rows g*64 + hu.
    // lay0: [0]=Whh0 k0-31 [1]=Whh0 k32-63 [2]=Wih0 (5 of 32; zero q!=0) [3]=0
    // lay1: [0]=Wih1 k0-31 [1]=Wih1 k32-63 [2]=Whh1 k0-31 [3]=Whh1 k32-63
    f16x8 Bf[4][4];
    f32x4 bC[4];
    #pragma unroll
    for (int g = 0; g < 4; ++g) {
        const int   row = g * 64 + hu;
        const float sg  = sgl[g];
        const float* Wa = lay ? (Wih1 + row * H) : (Whh0 + row * H);
        f16x8 f0, f1, f2, f3;
        #pragma unroll
        for (int j = 0; j < 8; ++j) {
            f0[j] = (_Float16)(Wa[q * 8 + j] * sg);
            f1[j] = (_Float16)(Wa[32 + q * 8 + j] * sg);
        }
        if (lay) {
            const float* Wb = Whh1 + row * H;
            #pragma unroll
            for (int j = 0; j < 8; ++j) {
                f2[j] = (_Float16)(Wb[q * 8 + j] * sg);
                f3[j] = (_Float16)(Wb[32 + q * 8 + j] * sg);
            }
        } else {
            #pragma unroll
            for (int j = 0; j < 8; ++j) {
                const int kk = q * 8 + j;
                f2[j] = (_Float16)(kk < DIN ? Wih0[row * DIN + kk] * sg : 0.0f);
                f3[j] = (_Float16)0.0f;
            }
        }
        Bf[g][0] = f0; Bf[g][1] = f1; Bf[g][2] = f2; Bf[g][3] = f3;
        const float bb = (lay ? (bih1[row] + bhh1[row])
                              : (bih0[row] + bhh0[row])) * sg;
        bC[g] = f32x4{bb, bb, bb, bb};
    }

    const int ab    = (col >> 2) * RSTR + q * 8;   // A-frag read base (halves)
    const int wslot = q * RSTR + hu;               // h write slot within ring

    __syncthreads();   // rings zeroed, flags zeroed; pipeline starts

    if (lay == 0) {
        // ================= layer-1 group =================
        const float* xp = x + (size_t)(b0 + (col >> 2)) * TSEQ * DIN;
        f16x8 ax = {(_Float16)0.0f, (_Float16)0.0f, (_Float16)0.0f, (_Float16)0.0f,
                    (_Float16)0.0f, (_Float16)0.0f, (_Float16)0.0f, (_Float16)0.0f};
        f32x4 dx[4];
        if (q == 0) {   // x(t=0)
            ax[0] = (_Float16)xp[0]; ax[1] = (_Float16)xp[1];
            ax[2] = (_Float16)xp[2]; ax[3] = (_Float16)xp[3];
            ax[4] = (_Float16)xp[4];
        }
        #pragma unroll
        for (int g = 0; g < 4; ++g)
            dx[g] = __builtin_amdgcn_mfma_f32_16x16x32_f16(ax, Bf[g][2], bC[g], 0, 0, 0);
        xp += DIN;

        float cst = 0.0f;
        int s1 = 0, s2 = 0;
        #pragma unroll 1
        for (int t = 0; t < TSEQ; ++t) {
            if (s1 < t) s1 = wait_min_ge(flg, t);           // h1(t-1) from own group

            const bool xld = (q == 0) && (t + 1 < TSEQ);
            float x0, x1, x2, x3, x4;
            if (xld) { x0 = xp[0]; x1 = xp[1]; x2 = xp[2]; x3 = xp[3]; x4 = xp[4]; }

            const _Float16* rb = ring1[(t + DEP - 1) & (DEP - 1)];
            f16x8 a0 = *(const f16x8*)&rb[ab];        // h1(t-1) k 0..31
            f16x8 a1 = *(const f16x8*)&rb[ab + 32];   // h1(t-1) k 32..63
            f32x4 d[4];
            #pragma unroll
            for (int g = 0; g < 4; ++g) {             // 2-deep chain (dx has x+bias)
                d[g] = __builtin_amdgcn_mfma_f32_16x16x32_f16(a0, Bf[g][0], dx[g], 0, 0, 0);
                d[g] = __builtin_amdgcn_mfma_f32_16x16x32_f16(a1, Bf[g][1], d[g], 0, 0, 0);
            }

            // WAR: slot t&3 still being read by lay-2 timestep t-DEP?
            if (t >= DEP && s2 < t - DEP + 1) s2 = wait_min_ge(flg + 4, t - DEP + 1);

            float iv = sigm2(d[0][0]);
            float fv = sigm2(d[1][0]);
            float gv = tanh2(d[2][0]);
            float ov = sigm2(d[3][0]);
            cst = fmaf(fv, cst, iv * gv);
            ring1[t & (DEP - 1)][wslot] = (_Float16)(ov * tanh2(2.0f * LOG2E * cst));
            __threadfence_block();                     // h1 write visible before flag
            if (lane == 0) ((volatile int*)flg)[ww] = t + 1;

            // prep dx for t+1 (off the critical path)
            if (xld) {
                ax[0] = (_Float16)x0; ax[1] = (_Float16)x1;
                ax[2] = (_Float16)x2; ax[3] = (_Float16)x3;
                ax[4] = (_Float16)x4;
            }
            #pragma unroll
            for (int g = 0; g < 4; ++g)
                dx[g] = __builtin_amdgcn_mfma_f32_16x16x32_f16(ax, Bf[g][2], bC[g], 0, 0, 0);
            xp += DIN;
        }
    } else {
        // ================= layer-2 group =================
        float cst = 0.0f, h2fin = 0.0f;
        int m1 = 0, m2 = 0;
        #pragma unroll 1
        for (int t = 0; t < TSEQ; ++t) {
            if (m2 < t) m2 = wait_min_ge(flg + 4, t);       // h2(t-1) from own group

            const _Float16* rh = ring2[(t + DEP - 1) & (DEP - 1)];
            f16x8 ah0 = *(const f16x8*)&rh[ab];       // h2(t-1) k 0..31
            f16x8 ah1 = *(const f16x8*)&rh[ab + 32];  // h2(t-1) k 32..63
            f32x4 d[4];
            #pragma unroll
            for (int g = 0; g < 4; ++g) {             // h2 part first (y1 not needed yet)
                d[g] = __builtin_amdgcn_mfma_f32_16x16x32_f16(ah0, Bf[g][2], bC[g], 0, 0, 0);
                d[g] = __builtin_amdgcn_mfma_f32_16x16x32_f16(ah1, Bf[g][3], d[g], 0, 0, 0);
            }

            if (m1 < t + 1) m1 = wait_min_ge(flg, t + 1);   // y1(t) from lay-1 group
            const _Float16* ry = ring1[t & (DEP - 1)];
            f16x8 ay0 = *(const f16x8*)&ry[ab];       // y1(t) k 0..31
            f16x8 ay1 = *(const f16x8*)&ry[ab + 32];  // y1(t) k 32..63
            #pragma unroll
            for (int g = 0; g < 4; ++g) {
                d[g] = __builtin_amdgcn_mfma_f32_16x16x32_f16(ay0, Bf[g][0], d[g], 0, 0, 0);
                d[g] = __builtin_amdgcn_mfma_f32_16x16x32_f16(ay1, Bf[g][1], d[g], 0, 0, 0);
            }

            float iv = sigm2(d[0][0]);
            float fv = sigm2(d[1][0]);
            float gv = tanh2(d[2][0]);
            float ov = sigm2(d[3][0]);
            cst = fmaf(fv, cst, iv * gv);
            h2fin = ov * tanh2(2.0f * LOG2E * cst);
            ring2[t & (DEP - 1)][wslot] = (_Float16)h2fin;
            __threadfence_block();
            if (lane == 0) ((volatile int*)flg)[4 + ww] = t + 1;
        }
        h2f[q][hu] = h2fin;
    }

    __syncthreads();

    // ---------------- epilogue: out = relu(h2(T-1) @ Wfc^T + bfc) ----------------
    {
        const int e = tid >> 7;            // 0..3
        const int o = tid & (NOUT - 1);    // 0..127
        const float4* wr = (const float4*)(Wfc + o * H);
        const float*  hv = h2f[e];
        float s0 = 0.f, s1 = 0.f, s2 = 0.f, s3 = 0.f;
        #pragma unroll
        for (int k = 0; k < H / 4; ++k) {
            float4 wv = wr[k];
            s0 = fmaf(wv.x, hv[4 * k + 0], s0);
            s1 = fmaf(wv.y, hv[4 * k + 1], s1);
            s2 = fmaf(wv.z, hv[4 * k + 2], s2);
            s3 = fmaf(wv.w, hv[4 * k + 3], s3);
        }
        float acc = bfc[o] + (s0 + s1) + (s2 + s3);
        out[(size_t)(b0 + e) * NOUT + o] = fmaxf(acc, 0.0f);
    }
}

extern "C" void kernel_launch(void* const* d_in, const int* in_sizes, int n_in,
                              void* d_out, int out_size, void* d_ws, size_t ws_size,
                              hipStream_t stream) {
    const float* x    = (const float*)d_in[0];
    const float* Wih0 = (const float*)d_in[1];
    const float* Whh0 = (const float*)d_in[2];
    const float* bih0 = (const float*)d_in[3];
    const float* bhh0 = (const float*)d_in[4];
    const float* Wih1 = (const float*)d_in[5];
    const float* Whh1 = (const float*)d_in[6];
    const float* bih1 = (const float*)d_in[7];
    const float* bhh1 = (const float*)d_in[8];
    const float* Wfc  = (const float*)d_in[9];
    const float* bfc  = (const float*)d_in[10];
    float* out = (float*)d_out;

    lstm_pipe<<<dim3(BATCH / BT), dim3(512), 0, stream>>>(
        x, Wih0, Whh0, bih0, bhh0, Wih1, Whh1, bih1, bhh1, Wfc, bfc, out);
}